// Round 1
// 901.549 us; speedup vs baseline: 1.6432x; 1.6432x over previous
//
#include <hip/hip_runtime.h>
#include <stdint.h>

// ---------------------------------------------------------------------------
// DiffTransformerLayer on MI355X (gfx950). ALL float I/O is FLOAT32 (per the
// harness contract). Outputs (f32): r2 [4,1024,1024], A [16,4,1024,1024].
// Internal GEMMs: bf16 MFMA 16x16x32, f32 accumulate.
// R1 changes vs prior best (1481 us):
//   1. fused scores+mask+softmax+(1-lam) kernel (removes 768 MB HBM traffic)
//   2. global_load_lds width-16 staging for bf16 GEMM operands (m97 lever)
//   3. FFN in 2 hidden-chunks of 2048 (1 accum pass instead of 3)
// Workspace peak: 48 MB. Vt + ff2 scratch live in d_out's r2 region.
// ---------------------------------------------------------------------------

typedef unsigned short u16;
typedef __attribute__((ext_vector_type(4))) float   floatx4;
typedef __attribute__((ext_vector_type(8))) __bf16  bf16x8;

#define LAMBDA_INIT_F 0.35550906759096926f
#define ONE_MINUS_LI  0.6444909324090307f

#define FLAG_OUT_BF16 1
#define FLAG_RELU     2
#define FLAG_BIAS     4
#define FLAG_SCALE    8
#define FLAG_MASK     16
#define FLAG_ACCUM    32
#define FLAG_BIAS_ROW 64
#define FLAG_LNH      128

__device__ __forceinline__ float bf2f(u16 u) {
    union { unsigned int i; float f; } w; w.i = ((unsigned int)u) << 16; return w.f;
}
__device__ __forceinline__ u16 f2bf(float f) {
    union { float f; unsigned int i; } w; w.f = f;
    unsigned int x = w.i;
    unsigned int r = x + 0x7fffu + ((x >> 16) & 1u);   // RNE
    return (u16)(r >> 16);
}
__device__ __forceinline__ float wred_sum(float v) {
#pragma unroll
    for (int off = 32; off > 0; off >>= 1) v += __shfl_xor(v, off, 64);
    return v;
}
// async global->LDS, 16B per lane; LDS dest = wave-uniform base + lane*16
__device__ __forceinline__ void gload_lds16(const u16* g, u16* l) {
    __builtin_amdgcn_global_load_lds(
        (const __attribute__((address_space(1))) unsigned int*)g,
        (__attribute__((address_space(3))) unsigned int*)l,
        16, 0, 0);
}

// ---------------------------------------------------------------------------
// Batched GEMM: C[m][n] = epilogue( sum_k A[m][k]*B[n][k] )
// A: [M][K] (lda), B: [N][K] (ldb). AF32/BF32: f32 operand, reg-staged with
// f32->bf16 convert. bf16 operands: global_load_lds width-16 into linear
// [128][32] LDS (m97 structure).
// Tile 128x128, BK=32, 256 threads (2x2 waves, 4x4 16x16x32 mfma frags).
// FLAG_LNH: grid.x==1, N==128: fused per-row LayerNorm over the 128 cols,
//           *(1-LAMBDA_INIT), bf16 store.
// ---------------------------------------------------------------------------
template <int FLAGS, int AF32, int BF32>
__global__ __launch_bounds__(256) void gemm_bt(
    const void* __restrict__ Ap, long long lda, long long sAh, long long sAb,
    const void* __restrict__ Bp, long long ldb, long long sBh, long long sBb,
    void* __restrict__ C, long long ldc, long long sCh, long long sCb,
    int K, int nb, float scale,
    const float* __restrict__ biasA, const float* __restrict__ biasB,
    int biasSplit, int biasRowStride,
    const int* __restrict__ mask, int maskS,
    const float* __restrict__ lnw, const float* __restrict__ lnb)
{
    const int z  = blockIdx.z;
    const int hz = z / nb, bz = z % nb;
    const long long aoff = hz * sAh + bz * sAb;
    const long long boff = hz * sBh + bz * sBb;
    const long long coff = hz * sCh + bz * sCb;

    __shared__ __attribute__((aligned(16))) u16 As[128 * 32];  // linear, DMA-compatible
    __shared__ __attribute__((aligned(16))) u16 Bs[128 * 32];

    const int tid  = threadIdx.x;
    const int lane = tid & 63;
    const int wid  = tid >> 6;
    const int wm   = wid >> 1, wn = wid & 1;
    const int m0   = blockIdx.y * 128;
    const int n0   = blockIdx.x * 128;
    const int sr   = tid >> 1;         // f32 staging row 0..127
    const int sc   = (tid & 1) * 16;   // f32 staging col 0/16
    const int dr   = (wid << 5) + (lane >> 2);  // DMA row 0..127 (32/wave over 2 calls)
    const int dk   = (lane & 3) << 3;           // DMA k-offset (u16)

    floatx4 acc[4][4];
#pragma unroll
    for (int i = 0; i < 4; i++)
#pragma unroll
        for (int j = 0; j < 4; j++) acc[i][j] = (floatx4){0.f, 0.f, 0.f, 0.f};

    const int lr = lane & 15;  // frag row (A) / col (B)
    const int q  = lane >> 4;  // k-quad

    for (int k0 = 0; k0 < K; k0 += 32) {
        u16 ta[16], tb[16];
        if constexpr (AF32) {
            const float* ga = (const float*)Ap + aoff + (long long)(m0 + sr) * lda + (k0 + sc);
            float4 f0 = *(const float4*)(ga);
            float4 f1 = *(const float4*)(ga + 4);
            float4 f2 = *(const float4*)(ga + 8);
            float4 f3 = *(const float4*)(ga + 12);
            ta[0]=f2bf(f0.x); ta[1]=f2bf(f0.y); ta[2]=f2bf(f0.z); ta[3]=f2bf(f0.w);
            ta[4]=f2bf(f1.x); ta[5]=f2bf(f1.y); ta[6]=f2bf(f1.z); ta[7]=f2bf(f1.w);
            ta[8]=f2bf(f2.x); ta[9]=f2bf(f2.y); ta[10]=f2bf(f2.z); ta[11]=f2bf(f2.w);
            ta[12]=f2bf(f3.x); ta[13]=f2bf(f3.y); ta[14]=f2bf(f3.z); ta[15]=f2bf(f3.w);
        }
        if constexpr (BF32) {
            const float* gb = (const float*)Bp + boff + (long long)(n0 + sr) * ldb + (k0 + sc);
            float4 f0 = *(const float4*)(gb);
            float4 f1 = *(const float4*)(gb + 4);
            float4 f2 = *(const float4*)(gb + 8);
            float4 f3 = *(const float4*)(gb + 12);
            tb[0]=f2bf(f0.x); tb[1]=f2bf(f0.y); tb[2]=f2bf(f0.z); tb[3]=f2bf(f0.w);
            tb[4]=f2bf(f1.x); tb[5]=f2bf(f1.y); tb[6]=f2bf(f1.z); tb[7]=f2bf(f1.w);
            tb[8]=f2bf(f2.x); tb[9]=f2bf(f2.y); tb[10]=f2bf(f2.z); tb[11]=f2bf(f2.w);
            tb[12]=f2bf(f3.x); tb[13]=f2bf(f3.y); tb[14]=f2bf(f3.z); tb[15]=f2bf(f3.w);
        }
        __syncthreads();   // previous iteration's frag reads done
        if constexpr (AF32) {
            *(uint4*)&As[sr * 32 + sc]     = *(uint4*)&ta[0];
            *(uint4*)&As[sr * 32 + sc + 8] = *(uint4*)&ta[8];
        } else {
            const u16* g = (const u16*)Ap + aoff + (long long)(m0 + dr) * lda + (k0 + dk);
            gload_lds16(g,              &As[wid << 10]);
            gload_lds16(g + (lda << 4), &As[(wid << 10) + 512]);
        }
        if constexpr (BF32) {
            *(uint4*)&Bs[sr * 32 + sc]     = *(uint4*)&tb[0];
            *(uint4*)&Bs[sr * 32 + sc + 8] = *(uint4*)&tb[8];
        } else {
            const u16* g = (const u16*)Bp + boff + (long long)(n0 + dr) * ldb + (k0 + dk);
            gload_lds16(g,              &Bs[wid << 10]);
            gload_lds16(g + (ldb << 4), &Bs[(wid << 10) + 512]);
        }
        __syncthreads();   // barrier drains vmcnt (DMA complete) + lgkm

        bf16x8 af[4], bfr[4];
#pragma unroll
        for (int i = 0; i < 4; i++) {
            union { uint4 u; bf16x8 v; } t;
            t.u = *(const uint4*)&As[(wm * 64 + i * 16 + lr) * 32 + q * 8];
            af[i] = t.v;
        }
#pragma unroll
        for (int j = 0; j < 4; j++) {
            union { uint4 u; bf16x8 v; } t;
            t.u = *(const uint4*)&Bs[(wn * 64 + j * 16 + lr) * 32 + q * 8];
            bfr[j] = t.v;
        }
#pragma unroll
        for (int i = 0; i < 4; i++)
#pragma unroll
            for (int j = 0; j < 4; j++)
                acc[i][j] = __builtin_amdgcn_mfma_f32_16x16x32_bf16(af[i], bfr[j], acc[i][j], 0, 0, 0);
    }

    // C/D layout: row = (lane>>4)*4 + r, col = lane&15 (m89-verified)
    const int rq = lane >> 4;
    const int cc = lane & 15;

    if constexpr (FLAGS & FLAG_LNH) {
        __shared__ float lnred[2][128][2];
        float s_[4][4], q_[4][4];
#pragma unroll
        for (int i = 0; i < 4; i++)
#pragma unroll
            for (int r = 0; r < 4; r++) {
                float s = 0.f, qq = 0.f;
#pragma unroll
                for (int j = 0; j < 4; j++) { float v = acc[i][j][r]; s += v; qq += v * v; }
                s_[i][r] = s; q_[i][r] = qq;
            }
#pragma unroll
        for (int off = 1; off < 16; off <<= 1)
#pragma unroll
            for (int i = 0; i < 4; i++)
#pragma unroll
                for (int r = 0; r < 4; r++) {
                    s_[i][r] += __shfl_xor(s_[i][r], off, 64);
                    q_[i][r] += __shfl_xor(q_[i][r], off, 64);
                }
        if (cc == 0) {
#pragma unroll
            for (int i = 0; i < 4; i++)
#pragma unroll
                for (int r = 0; r < 4; r++) {
                    const int row = wm * 64 + i * 16 + rq * 4 + r;
                    lnred[wn][row][0] = s_[i][r];
                    lnred[wn][row][1] = q_[i][r];
                }
        }
        __syncthreads();
#pragma unroll
        for (int i = 0; i < 4; i++)
#pragma unroll
            for (int r = 0; r < 4; r++) {
                const int row = wm * 64 + i * 16 + rq * 4 + r;
                const float sum = lnred[0][row][0] + lnred[1][row][0];
                const float sq  = lnred[0][row][1] + lnred[1][row][1];
                const float mu  = sum * (1.f / 128.f);
                const float var = sq * (1.f / 128.f) - mu * mu;
                const float inv = rsqrtf(var + 1e-5f);
#pragma unroll
                for (int j = 0; j < 4; j++) {
                    const int col = wn * 64 + j * 16 + cc;
                    const float v = ((acc[i][j][r] - mu) * inv * lnw[col] + lnb[col]) * ONE_MINUS_LI;
                    ((u16*)C)[coff + (long long)(m0 + row) * ldc + col] = f2bf(v);
                }
            }
        return;
    }

#pragma unroll
    for (int j = 0; j < 4; j++) {
        const int col = n0 + wn * 64 + j * 16 + cc;
        float cbv = 0.f;
        if constexpr (FLAGS & FLAG_BIAS)
            cbv = (col < biasSplit) ? biasA[col] : biasB[col - biasSplit];
        bool keep = true;
        if constexpr (FLAGS & FLAG_MASK) keep = (mask[bz * maskS + col] != 0);
#pragma unroll
        for (int i = 0; i < 4; i++) {
#pragma unroll
            for (int r = 0; r < 4; r++) {
                const int row = m0 + wm * 64 + i * 16 + rq * 4 + r;
                float v = acc[i][j][r];
                if constexpr (FLAGS & FLAG_SCALE) v *= scale;
                float bv = cbv;
                if constexpr (FLAGS & FLAG_BIAS_ROW) bv = biasA[hz * biasRowStride + row];
                v += bv;
                if constexpr (FLAGS & FLAG_RELU) v = fmaxf(v, 0.f);
                if constexpr (FLAGS & FLAG_MASK) { if (!keep) v = -__builtin_inff(); }
                const long long idx = coff + (long long)row * ldc + col;
                if constexpr (FLAGS & FLAG_OUT_BF16) {
                    ((u16*)C)[idx] = f2bf(v);
                } else {
                    float* Cf = (float*)C;
                    if constexpr (FLAGS & FLAG_ACCUM) v += Cf[idx];
                    Cf[idx] = v;
                }
            }
        }
    }
}

// ---------------------------------------------------------------------------
// Fused scores + mask + softmax + *(1-lam): per block, 16 Q-rows x all 1024 t.
// Swapped-operand QK^T (mfma(K,Q)) so each lane holds one full score row:
// lane: s = lane&15; per chunk c, t = w*256 + c*16 + (lane>>4)*4 + r.
// Row-reduce = in-lane (64 vals) + shfl_xor(16,32) + tiny LDS cross-wave.
// Writes A f32 ONCE (the required output); PV re-reads it.
// ---------------------------------------------------------------------------
__global__ __launch_bounds__(256) void scores_softmax(
    const u16* __restrict__ QK, const int* __restrict__ mask,
    float* __restrict__ Aout,
    const float* __restrict__ lq1, const float* __restrict__ lk1,
    const float* __restrict__ lq2, const float* __restrict__ lk2)
{
    const int tid  = threadIdx.x;
    const int lane = tid & 63;
    const int w    = tid >> 6;
    const int z    = blockIdx.z;       // h*4 + b
    const int h    = z >> 2, b = z & 3;
    const int r0   = blockIdx.x << 4;  // Q-row block (16 rows)

    __shared__ int   msk[1024];
    __shared__ float redM[4][16];
    __shared__ float redS[4][16];

    *(int4*)&msk[tid * 4] = *(const int4*)(mask + b * 1024 + tid * 4);

    // lambda scale (deterministic, identical in every wave)
    float d1 = lq1[lane] * lk1[lane];
    float d2 = lq2[lane] * lk2[lane];
    d1 = wred_sum(d1);
    d2 = wred_sum(d2);
    const float lamscale = 1.f - (expf(d1) - expf(d2) + LAMBDA_INIT_F);

    const int sl = lane & 15;   // load index within 16 (s for Q, t for K)
    const int kq = lane >> 4;   // k-quad on load; t-quad on output

    // Q frags (b-operand): row r0+sl, k = kq*8 (+32 for 2nd k-step)
    const u16* qbase = QK + (long long)(b * 1024 + r0 + sl) * 2048 + h * 64 + kq * 8;
    bf16x8 qf0, qf1;
    {
        union { uint4 u; bf16x8 v; } t;
        t.u = *(const uint4*)(qbase);      qf0 = t.v;
        t.u = *(const uint4*)(qbase + 32); qf1 = t.v;
    }
    const u16* kbase = QK + (long long)(b * 1024) * 2048 + 1024 + h * 64 + kq * 8;

    floatx4 acc[16];
    __syncthreads();   // msk staged

#pragma unroll
    for (int c = 0; c < 16; c++) {
        const int t = (w << 8) + (c << 4) + sl;
        union { uint4 u; bf16x8 v; } k0_, k1_;
        k0_.u = *(const uint4*)(kbase + (long long)t * 2048);
        k1_.u = *(const uint4*)(kbase + (long long)t * 2048 + 32);
        floatx4 a = (floatx4){0.f, 0.f, 0.f, 0.f};
        a = __builtin_amdgcn_mfma_f32_16x16x32_bf16(k0_.v, qf0, a, 0, 0, 0);
        a = __builtin_amdgcn_mfma_f32_16x16x32_bf16(k1_.v, qf1, a, 0, 0, 0);
        acc[c] = a;
    }

    // scale + mask, row max
    float mx = -__builtin_inff();
#pragma unroll
    for (int c = 0; c < 16; c++) {
        const int tb_ = (w << 8) + (c << 4) + (kq << 2);
        int4 m4 = *(const int4*)&msk[tb_];
#pragma unroll
        for (int r = 0; r < 4; r++) {
            const int mv = (r == 0) ? m4.x : (r == 1) ? m4.y : (r == 2) ? m4.z : m4.w;
            float x = (mv != 0) ? acc[c][r] * 0.03125f : -__builtin_inff();
            acc[c][r] = x;
            mx = fmaxf(mx, x);
        }
    }
    mx = fmaxf(mx, __shfl_xor(mx, 16, 64));
    mx = fmaxf(mx, __shfl_xor(mx, 32, 64));
    if (lane < 16) redM[w][lane] = mx;
    __syncthreads();
    mx = fmaxf(fmaxf(redM[0][sl], redM[1][sl]), fmaxf(redM[2][sl], redM[3][sl]));

    // exp + sum
    float s = 0.f;
#pragma unroll
    for (int c = 0; c < 16; c++)
#pragma unroll
        for (int r = 0; r < 4; r++) {
            const float e = __expf(acc[c][r] - mx);
            acc[c][r] = e;
            s += e;
        }
    s += __shfl_xor(s, 16, 64);
    s += __shfl_xor(s, 32, 64);
    if (lane < 16) redS[w][lane] = s;
    __syncthreads();
    s = redS[0][sl] + redS[1][sl] + redS[2][sl] + redS[3][sl];
    const float sc = lamscale / s;

    float* obase = Aout + (long long)z * 1048576
                 + (long long)(r0 + sl) * 1024 + (w << 8) + (kq << 2);
#pragma unroll
    for (int c = 0; c < 16; c++) {
        floatx4 o = acc[c] * sc;
        *(floatx4*)(obase + (c << 4)) = o;
    }
}

// ---------------------------------------------------------------------------
// Pack kernels (f32 in -> bf16 out)
// ---------------------------------------------------------------------------
// Xbf[i] = bf16(X[i]), 4 elems/thread
__global__ void pack_x(const float* __restrict__ X, u16* __restrict__ dst)
{
    const int i = (blockIdx.x * 256 + threadIdx.x) * 4;
    float4 f = *(const float4*)(X + i);
    u16 o[4] = { f2bf(f.x), f2bf(f.y), f2bf(f.z), f2bf(f.w) };
    *(uint2*)(dst + i) = *(const uint2*)&o[0];
}

// WqkT [2048 n][1024 k]: n<1024 -> WQ1[h=n>>6][k][e=n&63]; else WK1
__global__ void pack_wqkt(const float* __restrict__ WQ, const float* __restrict__ WK,
                          u16* __restrict__ dst)
{
    int i = blockIdx.x * 256 + threadIdx.x;  // 2M
    int k = i & 1023;
    int n = i >> 10;
    float v;
    if (n < 1024) {
        int h = n >> 6, e = n & 63;
        v = WQ[(h * 1024 + k) * 64 + e];
    } else {
        int m = n - 1024; int h = m >> 6, e = m & 63;
        v = WK[(h * 1024 + k) * 64 + e];
    }
    dst[i] = f2bf(v);
}

// WvT [16 h][128 v][1024 d] = WV[h][d][v]
__global__ void pack_wvt(const float* __restrict__ WV, u16* __restrict__ dst)
{
    int i = blockIdx.x * 256 + threadIdx.x;  // 2M
    int d = i & 1023;
    int v = (i >> 10) & 127;
    int h = i >> 17;
    dst[i] = f2bf(WV[(h * 1024 + d) * 128 + v]);
}

// dst[C][R] = bf16(src[R][C]), R = 1<<rlog2
__global__ void transpose_bf(const float* __restrict__ src, u16* __restrict__ dst,
                             int rlog2, int C)
{
    long long i = (long long)blockIdx.x * 256 + threadIdx.x;
    int r = (int)(i & ((1 << rlog2) - 1));
    int c = (int)(i >> rlog2);
    dst[i] = f2bf(src[(long long)r * C + c]);
}

// out = LN(x + add) over 1024; x/add each f32 or bf16 (null-select); out bf16 or f32.
__global__ __launch_bounds__(256) void ln_residual(
    const float* __restrict__ xf, const u16* __restrict__ xbf,
    const float* __restrict__ addf, const u16* __restrict__ addbf,
    const float* __restrict__ w, const float* __restrict__ bb,
    u16* __restrict__ obf, float* __restrict__ of32)
{
    const int row = blockIdx.x;
    const int tid = threadIdx.x;
    const int lane = tid & 63, wid = tid >> 6;
    const long long base = (long long)row * 1024;
    float v[4];
    float s = 0.f;
#pragma unroll
    for (int i = 0; i < 4; i++) {
        const int c = tid * 4 + i;
        float x = xf ? xf[base + c] : bf2f(xbf[base + c]);
        x += addf ? addf[base + c] : bf2f(addbf[base + c]);
        v[i] = x; s += x;
    }
    __shared__ float red[8];
    s = wred_sum(s);
    if (lane == 0) red[wid] = s;
    __syncthreads();
    const float mu = (red[0] + red[1] + red[2] + red[3]) * (1.f / 1024.f);
    float ss = 0.f;
#pragma unroll
    for (int i = 0; i < 4; i++) { const float d = v[i] - mu; ss += d * d; }
    ss = wred_sum(ss);
    if (lane == 0) red[wid + 4] = ss;
    __syncthreads();
    const float var = (red[4] + red[5] + red[6] + red[7]) * (1.f / 1024.f);
    const float inv = rsqrtf(var + 1e-5f);
#pragma unroll
    for (int i = 0; i < 4; i++) {
        const int c = tid * 4 + i;
        const float o = (v[i] - mu) * inv * w[c] + bb[c];
        if (obf) obf[base + c] = f2bf(o);
        else     of32[base + c] = o;
    }
}

// ---------------------------------------------------------------------------
extern "C" void kernel_launch(void* const* d_in, const int* in_sizes, int n_in,
                              void* d_out, int out_size, void* d_ws, size_t ws_size,
                              hipStream_t stream)
{
    const float* X     = (const float*)d_in[0];   // [4,1024,1024]
    const int*   mask  = (const int*)d_in[1];     // [4,1024]
    const float* WQ1   = (const float*)d_in[2];
    const float* bQ1   = (const float*)d_in[3];
    const float* WK1   = (const float*)d_in[4];
    const float* bK1   = (const float*)d_in[5];
    const float* WV    = (const float*)d_in[6];
    const float* bV    = (const float*)d_in[7];
    const float* lnh_w = (const float*)d_in[8];
    const float* lnh_b = (const float*)d_in[9];
    const float* WO    = (const float*)d_in[10];  // [2048,1024]
    const float* bO    = (const float*)d_in[11];
    const float* ln1_w = (const float*)d_in[12];
    const float* ln1_b = (const float*)d_in[13];
    const float* ln2_w = (const float*)d_in[14];
    const float* ln2_b = (const float*)d_in[15];
    const float* W1    = (const float*)d_in[16];  // [1024,4096]
    const float* b1    = (const float*)d_in[17];
    const float* W2    = (const float*)d_in[18];  // [4096,1024]
    const float* b2    = (const float*)d_in[19];
    const float* lq1   = (const float*)d_in[20];
    const float* lk1   = (const float*)d_in[21];
    const float* lq2   = (const float*)d_in[22];
    const float* lk2   = (const float*)d_in[23];

    float* r2   = (float*)d_out;              // [4096,1024] f32, written LAST
    float* Aout = (float*)d_out + 4194304;    // [16,4,1024,1024] f32
    u16*   Vt   = (u16*)d_out;                // Vt scratch in r2 region, dead after PV
    float* ff2  = (float*)d_out;              // ff2 scratch in r2 region, after PV

    // Workspace arena, 48 MB peak (byte offsets; lifetimes in step numbers):
    uint8_t* wp = (uint8_t*)d_ws;
    const size_t MB = 1024 * 1024;
    u16*   WqkT = (u16*)(wp + 0);          //  0..4   [1-3]
    u16*   WvT  = (u16*)(wp + 4 * MB);     //  4..8   [2-4]
    u16*   QK   = (u16*)(wp + 8 * MB);     //  8..24  [3-6]
    u16*   Xbf  = (u16*)(wp + 24 * MB);    // 24..32  [0-4]
    u16*   WOt  = (u16*)(wp + 0);          //  0..4   [5-8]
    u16*   Ocat = (u16*)(wp + 24 * MB);    // 24..40  [7-8]
    u16*   attnb= (u16*)(wp + 8 * MB);     //  8..16  [8-9]
    u16*   h1   = (u16*)(wp + 40 * MB);    // 40..48  [9-12]
    u16*   W1t  = (u16*)(wp + 16 * MB);    // 16..24  [10-11]
    u16*   W2t  = (u16*)(wp + 32 * MB);    // 32..40  [10-11]
    u16*   ff1c = (u16*)(wp + 0);          //  0..16  [11]
    (void)ws_size; (void)in_sizes; (void)n_in; (void)out_size;

    const long long Z = 0;
    const int NOSPLIT = 1 << 30;

    // 0-2. packs
    pack_x<<<4096, 256, 0, stream>>>(X, Xbf);
    pack_wqkt<<<8192, 256, 0, stream>>>(WQ1, WK1, WqkT);
    pack_wvt<<<8192, 256, 0, stream>>>(WV, WvT);

    // 3. QK = Xbf[4096,1024] x WqkT^T + [bQ1|bK1] -> bf16 [4096,2048]
    gemm_bt<FLAG_OUT_BF16 | FLAG_BIAS, 0, 0><<<dim3(16, 32, 1), 256, 0, stream>>>(
        Xbf, 1024, Z, Z, WqkT, 1024, Z, Z, QK, 2048, Z, Z,
        1024, 1, 1.f, bQ1, bK1, 1024, 0, nullptr, 0, nullptr, nullptr);

    // 4. Vt[h][b][v][t] = WvT[h] x Xbf[b]^T + bV[h][v] -> bf16 (in r2 region)
    gemm_bt<FLAG_OUT_BF16 | FLAG_BIAS_ROW, 0, 0><<<dim3(8, 1, 64), 256, 0, stream>>>(
        WvT, 1024, 131072LL, Z, Xbf, 1024, Z, 1048576LL,
        Vt, 1024, 524288LL, 131072LL,
        1024, 4, 1.f, bV, nullptr, NOSPLIT, 128, nullptr, 0, nullptr, nullptr);

    // 5. WOt pack (WqkT region, dead)
    transpose_bf<<<8192, 256, 0, stream>>>(WO, WOt, 11, 1024);

    // 6. fused scores+mask+softmax+(1-lam): A f32 written once
    scores_softmax<<<dim3(64, 1, 64), 256, 0, stream>>>(QK, mask, Aout,
                                                        lq1, lk1, lq2, lk2);

    // 7. PV + fused per-head LN: per (h,b) A[1024,1024](f32) x Vt[128,1024]^T
    //    -> LN(128), *(1-LAMBDA_INIT), scatter to Ocat[b][s][h*128+c] bf16
    gemm_bt<FLAG_LNH, 1, 0><<<dim3(1, 8, 64), 256, 0, stream>>>(
        Aout, 1024, 4194304LL, 1048576LL, Vt, 1024, 524288LL, 131072LL,
        Ocat, 2048, 128LL, 2097152LL,
        1024, 4, 1.f, nullptr, nullptr, NOSPLIT, 0, nullptr, 0, lnh_w, lnh_b);

    // 8. attn = Ocat[4096,2048] x WOt^T + bO -> bf16
    gemm_bt<FLAG_OUT_BF16 | FLAG_BIAS, 0, 0><<<dim3(8, 32, 1), 256, 0, stream>>>(
        Ocat, 2048, Z, Z, WOt, 2048, Z, Z, attnb, 1024, Z, Z,
        2048, 1, 1.f, bO, nullptr, NOSPLIT, 0, nullptr, 0, nullptr, nullptr);

    // 9. h1 = LN(X(f32) + attn(bf16)) -> bf16
    ln_residual<<<4096, 256, 0, stream>>>(X, nullptr, nullptr, attnb,
                                          ln1_w, ln1_b, h1, nullptr);

    // 10. W1t/W2t packs (QK-tail / Ocat regions, dead)
    transpose_bf<<<16384, 256, 0, stream>>>(W1, W1t, 10, 4096);
    transpose_bf<<<16384, 256, 0, stream>>>(W2, W2t, 12, 1024);

    // 11. FFN in 2 hidden-chunks of 2048; ff2 f32 accumulates in r2 region
    for (int c = 0; c < 2; c++) {
        gemm_bt<FLAG_OUT_BF16 | FLAG_BIAS | FLAG_RELU, 0, 0><<<dim3(16, 32, 1), 256, 0, stream>>>(
            h1, 1024, Z, Z, W1t + (long long)c * 2097152, 1024, Z, Z,
            ff1c, 2048, Z, Z,
            1024, 1, 1.f, b1 + c * 2048, nullptr, NOSPLIT, 0, nullptr, 0, nullptr, nullptr);
        if (c == 0) {
            gemm_bt<FLAG_BIAS, 0, 0><<<dim3(8, 32, 1), 256, 0, stream>>>(
                ff1c, 2048, Z, Z, W2t + c * 2048, 4096, Z, Z, ff2, 1024, Z, Z,
                2048, 1, 1.f, b2, nullptr, NOSPLIT, 0, nullptr, 0, nullptr, nullptr);
        } else {
            gemm_bt<FLAG_ACCUM, 0, 0><<<dim3(8, 32, 1), 256, 0, stream>>>(
                ff1c, 2048, Z, Z, W2t + c * 2048, 4096, Z, Z, ff2, 1024, Z, Z,
                2048, 1, 1.f, nullptr, nullptr, NOSPLIT, 0, nullptr, 0, nullptr, nullptr);
        }
    }

    // 12. r2 = LN(h1(bf16) + ff2(f32)) -> f32 d_out (in place over ff2: each
    //     thread reads its elements before writing them; no cross-thread alias)
    ln_residual<<<4096, 256, 0, stream>>>(nullptr, h1, ff2, nullptr,
                                          ln2_w, ln2_b, nullptr, r2);
}

// Round 2
// 884.326 us; speedup vs baseline: 1.6752x; 1.0195x over previous
//
#include <hip/hip_runtime.h>
#include <stdint.h>

// ---------------------------------------------------------------------------
// DiffTransformerLayer on MI355X (gfx950). ALL float I/O is FLOAT32 (per the
// harness contract). Outputs (f32): r2 [4,1024,1024], A [16,4,1024,1024].
// Internal GEMMs: bf16 MFMA 16x16x32, f32 accumulate.
// R2 changes vs R1 (901 us):
//   1. gemm_bt BK=32->64: half the barrier/vmcnt-drain count per K
//   2. XOR-swizzled LDS (rule #21: pre-swizzled GLOBAL source for the DMA
//      path, linear LDS dest, XOR'd frag reads) -> 8-way bank conflict
//      on ds_read_b128 becomes 2-way (free per m136)
// Workspace peak: 48 MB. Vt + ff2 scratch live in d_out's r2 region.
// ---------------------------------------------------------------------------

typedef unsigned short u16;
typedef __attribute__((ext_vector_type(4))) float   floatx4;
typedef __attribute__((ext_vector_type(8))) __bf16  bf16x8;

#define LAMBDA_INIT_F 0.35550906759096926f
#define ONE_MINUS_LI  0.6444909324090307f

#define FLAG_OUT_BF16 1
#define FLAG_RELU     2
#define FLAG_BIAS     4
#define FLAG_SCALE    8
#define FLAG_MASK     16
#define FLAG_ACCUM    32
#define FLAG_BIAS_ROW 64
#define FLAG_LNH      128

__device__ __forceinline__ float bf2f(u16 u) {
    union { unsigned int i; float f; } w; w.i = ((unsigned int)u) << 16; return w.f;
}
__device__ __forceinline__ u16 f2bf(float f) {
    union { float f; unsigned int i; } w; w.f = f;
    unsigned int x = w.i;
    unsigned int r = x + 0x7fffu + ((x >> 16) & 1u);   // RNE
    return (u16)(r >> 16);
}
__device__ __forceinline__ float wred_sum(float v) {
#pragma unroll
    for (int off = 32; off > 0; off >>= 1) v += __shfl_xor(v, off, 64);
    return v;
}
// async global->LDS, 16B per lane; LDS dest = wave-uniform base + lane*16
__device__ __forceinline__ void gload_lds16(const u16* g, u16* l) {
    __builtin_amdgcn_global_load_lds(
        (const __attribute__((address_space(1))) unsigned int*)g,
        (__attribute__((address_space(3))) unsigned int*)l,
        16, 0, 0);
}
// 32 consecutive f32 -> 32 bf16
__device__ __forceinline__ void ld32f_bf(const float* g, u16* o) {
#pragma unroll
    for (int m = 0; m < 8; m++) {
        float4 f = *(const float4*)(g + m * 4);
        o[m * 4 + 0] = f2bf(f.x); o[m * 4 + 1] = f2bf(f.y);
        o[m * 4 + 2] = f2bf(f.z); o[m * 4 + 3] = f2bf(f.w);
    }
}

// ---------------------------------------------------------------------------
// Batched GEMM: C[m][n] = epilogue( sum_k A[m][k]*B[n][k] )
// A: [M][K] (lda), B: [N][K] (ldb). AF32/BF32: f32 operand, reg-staged with
// f32->bf16 convert + swizzled ds_write. bf16 operands: global_load_lds
// width-16 with pre-swizzled global source (rule #21), linear LDS dest.
// LDS layout invariant: Xs[row][s] holds logical X[row][s ^ ((row&7)<<3)]
// (u16 col units; row stride 64 u16 = 128 B). Frag reads XOR the col back.
// Tile 128x128, BK=64, 256 threads (2x2 waves, 4x4 16x16x32 mfma frags,
// 2 k-substeps per K-iteration => 32 MFMA per barrier pair).
// FLAG_LNH: grid.x==1, N==128: fused per-row LayerNorm over the 128 cols,
//           *(1-LAMBDA_INIT), bf16 store.
// ---------------------------------------------------------------------------
template <int FLAGS, int AF32, int BF32>
__global__ __launch_bounds__(256) void gemm_bt(
    const void* __restrict__ Ap, long long lda, long long sAh, long long sAb,
    const void* __restrict__ Bp, long long ldb, long long sBh, long long sBb,
    void* __restrict__ C, long long ldc, long long sCh, long long sCb,
    int K, int nb, float scale,
    const float* __restrict__ biasA, const float* __restrict__ biasB,
    int biasSplit, int biasRowStride,
    const int* __restrict__ mask, int maskS,
    const float* __restrict__ lnw, const float* __restrict__ lnb)
{
    const int z  = blockIdx.z;
    const int hz = z / nb, bz = z % nb;
    const long long aoff = hz * sAh + bz * sAb;
    const long long boff = hz * sBh + bz * sBb;
    const long long coff = hz * sCh + bz * sCb;

    __shared__ __attribute__((aligned(16))) u16 As[128 * 64];
    __shared__ __attribute__((aligned(16))) u16 Bs[128 * 64];

    const int tid  = threadIdx.x;
    const int lane = tid & 63;
    const int wid  = tid >> 6;
    const int wm   = wid >> 1, wn = wid & 1;
    const int m0   = blockIdx.y * 128;
    const int n0   = blockIdx.x * 128;
    // f32 reg-staging: thread -> row tid>>1, col-half (tid&1)*32 (u16)
    const int sr   = tid >> 1;
    const int sh   = (tid & 1) * 32;
    const int srx  = (sr & 7) << 3;            // store-side row XOR
    // DMA staging: lane -> row-in-8-group lane>>3, pre-swizzled source col
    const int drow = lane >> 3;
    const int dcol = ((lane & 7) ^ drow) << 3;

    floatx4 acc[4][4];
#pragma unroll
    for (int i = 0; i < 4; i++)
#pragma unroll
        for (int j = 0; j < 4; j++) acc[i][j] = (floatx4){0.f, 0.f, 0.f, 0.f};

    const int lr   = lane & 15;  // frag row (A) / col (B)
    const int q    = lane >> 4;  // k-quad
    const int rxor = (lr & 7) << 3;            // read-side row XOR

    for (int k0 = 0; k0 < K; k0 += 64) {
        union { u16 u[32]; uint4 v[4]; } ta, tb;
        if constexpr (AF32)
            ld32f_bf((const float*)Ap + aoff + (long long)(m0 + sr) * lda + k0 + sh, ta.u);
        if constexpr (BF32)
            ld32f_bf((const float*)Bp + boff + (long long)(n0 + sr) * ldb + k0 + sh, tb.u);
        __syncthreads();   // previous iteration's frag reads done
        if constexpr (AF32) {
#pragma unroll
            for (int m = 0; m < 4; m++)
                *(uint4*)&As[sr * 64 + ((sh + m * 8) ^ srx)] = ta.v[m];
        } else {
            const u16* g = (const u16*)Ap + aoff
                         + (long long)(m0 + (wid << 5) + drow) * lda + k0 + dcol;
#pragma unroll
            for (int j = 0; j < 4; j++)
                gload_lds16(g + (long long)(j * 8) * lda, &As[((wid << 5) + j * 8) * 64]);
        }
        if constexpr (BF32) {
#pragma unroll
            for (int m = 0; m < 4; m++)
                *(uint4*)&Bs[sr * 64 + ((sh + m * 8) ^ srx)] = tb.v[m];
        } else {
            const u16* g = (const u16*)Bp + boff
                         + (long long)(n0 + (wid << 5) + drow) * ldb + k0 + dcol;
#pragma unroll
            for (int j = 0; j < 4; j++)
                gload_lds16(g + (long long)(j * 8) * ldb, &Bs[((wid << 5) + j * 8) * 64]);
        }
        __syncthreads();   // barrier drains vmcnt (DMA complete) + lgkm

#pragma unroll
        for (int ks = 0; ks < 2; ks++) {
            const int cb = ks * 32 + q * 8;
            bf16x8 af[4], bfr[4];
#pragma unroll
            for (int i = 0; i < 4; i++) {
                union { uint4 u; bf16x8 v; } t;
                t.u = *(const uint4*)&As[(wm * 64 + i * 16 + lr) * 64 + (cb ^ rxor)];
                af[i] = t.v;
            }
#pragma unroll
            for (int j = 0; j < 4; j++) {
                union { uint4 u; bf16x8 v; } t;
                t.u = *(const uint4*)&Bs[(wn * 64 + j * 16 + lr) * 64 + (cb ^ rxor)];
                bfr[j] = t.v;
            }
#pragma unroll
            for (int i = 0; i < 4; i++)
#pragma unroll
                for (int j = 0; j < 4; j++)
                    acc[i][j] = __builtin_amdgcn_mfma_f32_16x16x32_bf16(af[i], bfr[j], acc[i][j], 0, 0, 0);
        }
    }

    // C/D layout: row = (lane>>4)*4 + r, col = lane&15 (m89-verified)
    const int rq = lane >> 4;
    const int cc = lane & 15;

    if constexpr (FLAGS & FLAG_LNH) {
        __shared__ float lnred[2][128][2];
        float s_[4][4], q_[4][4];
#pragma unroll
        for (int i = 0; i < 4; i++)
#pragma unroll
            for (int r = 0; r < 4; r++) {
                float s = 0.f, qq = 0.f;
#pragma unroll
                for (int j = 0; j < 4; j++) { float v = acc[i][j][r]; s += v; qq += v * v; }
                s_[i][r] = s; q_[i][r] = qq;
            }
#pragma unroll
        for (int off = 1; off < 16; off <<= 1)
#pragma unroll
            for (int i = 0; i < 4; i++)
#pragma unroll
                for (int r = 0; r < 4; r++) {
                    s_[i][r] += __shfl_xor(s_[i][r], off, 64);
                    q_[i][r] += __shfl_xor(q_[i][r], off, 64);
                }
        if (cc == 0) {
#pragma unroll
            for (int i = 0; i < 4; i++)
#pragma unroll
                for (int r = 0; r < 4; r++) {
                    const int row = wm * 64 + i * 16 + rq * 4 + r;
                    lnred[wn][row][0] = s_[i][r];
                    lnred[wn][row][1] = q_[i][r];
                }
        }
        __syncthreads();
#pragma unroll
        for (int i = 0; i < 4; i++)
#pragma unroll
            for (int r = 0; r < 4; r++) {
                const int row = wm * 64 + i * 16 + rq * 4 + r;
                const float sum = lnred[0][row][0] + lnred[1][row][0];
                const float sq  = lnred[0][row][1] + lnred[1][row][1];
                const float mu  = sum * (1.f / 128.f);
                const float var = sq * (1.f / 128.f) - mu * mu;
                const float inv = rsqrtf(var + 1e-5f);
#pragma unroll
                for (int j = 0; j < 4; j++) {
                    const int col = wn * 64 + j * 16 + cc;
                    const float v = ((acc[i][j][r] - mu) * inv * lnw[col] + lnb[col]) * ONE_MINUS_LI;
                    ((u16*)C)[coff + (long long)(m0 + row) * ldc + col] = f2bf(v);
                }
            }
        return;
    }

#pragma unroll
    for (int j = 0; j < 4; j++) {
        const int col = n0 + wn * 64 + j * 16 + cc;
        float cbv = 0.f;
        if constexpr (FLAGS & FLAG_BIAS)
            cbv = (col < biasSplit) ? biasA[col] : biasB[col - biasSplit];
        bool keep = true;
        if constexpr (FLAGS & FLAG_MASK) keep = (mask[bz * maskS + col] != 0);
#pragma unroll
        for (int i = 0; i < 4; i++) {
#pragma unroll
            for (int r = 0; r < 4; r++) {
                const int row = m0 + wm * 64 + i * 16 + rq * 4 + r;
                float v = acc[i][j][r];
                if constexpr (FLAGS & FLAG_SCALE) v *= scale;
                float bv = cbv;
                if constexpr (FLAGS & FLAG_BIAS_ROW) bv = biasA[hz * biasRowStride + row];
                v += bv;
                if constexpr (FLAGS & FLAG_RELU) v = fmaxf(v, 0.f);
                if constexpr (FLAGS & FLAG_MASK) { if (!keep) v = -__builtin_inff(); }
                const long long idx = coff + (long long)row * ldc + col;
                if constexpr (FLAGS & FLAG_OUT_BF16) {
                    ((u16*)C)[idx] = f2bf(v);
                } else {
                    float* Cf = (float*)C;
                    if constexpr (FLAGS & FLAG_ACCUM) v += Cf[idx];
                    Cf[idx] = v;
                }
            }
        }
    }
}

// ---------------------------------------------------------------------------
// Fused scores + mask + softmax + *(1-lam): per block, 16 Q-rows x all 1024 t.
// Swapped-operand QK^T (mfma(K,Q)) so each lane holds one full score row:
// lane: s = lane&15; per chunk c, t = w*256 + c*16 + (lane>>4)*4 + r.
// Row-reduce = in-lane (64 vals) + shfl_xor(16,32) + tiny LDS cross-wave.
// Writes A f32 ONCE (the required output); PV re-reads it.
// ---------------------------------------------------------------------------
__global__ __launch_bounds__(256) void scores_softmax(
    const u16* __restrict__ QK, const int* __restrict__ mask,
    float* __restrict__ Aout,
    const float* __restrict__ lq1, const float* __restrict__ lk1,
    const float* __restrict__ lq2, const float* __restrict__ lk2)
{
    const int tid  = threadIdx.x;
    const int lane = tid & 63;
    const int w    = tid >> 6;
    const int z    = blockIdx.z;       // h*4 + b
    const int h    = z >> 2, b = z & 3;
    const int r0   = blockIdx.x << 4;  // Q-row block (16 rows)

    __shared__ int   msk[1024];
    __shared__ float redM[4][16];
    __shared__ float redS[4][16];

    *(int4*)&msk[tid * 4] = *(const int4*)(mask + b * 1024 + tid * 4);

    // lambda scale (deterministic, identical in every wave)
    float d1 = lq1[lane] * lk1[lane];
    float d2 = lq2[lane] * lk2[lane];
    d1 = wred_sum(d1);
    d2 = wred_sum(d2);
    const float lamscale = 1.f - (expf(d1) - expf(d2) + LAMBDA_INIT_F);

    const int sl = lane & 15;   // load index within 16 (s for Q, t for K)
    const int kq = lane >> 4;   // k-quad on load; t-quad on output

    // Q frags (b-operand): row r0+sl, k = kq*8 (+32 for 2nd k-step)
    const u16* qbase = QK + (long long)(b * 1024 + r0 + sl) * 2048 + h * 64 + kq * 8;
    bf16x8 qf0, qf1;
    {
        union { uint4 u; bf16x8 v; } t;
        t.u = *(const uint4*)(qbase);      qf0 = t.v;
        t.u = *(const uint4*)(qbase + 32); qf1 = t.v;
    }
    const u16* kbase = QK + (long long)(b * 1024) * 2048 + 1024 + h * 64 + kq * 8;

    floatx4 acc[16];
    __syncthreads();   // msk staged

#pragma unroll
    for (int c = 0; c < 16; c++) {
        const int t = (w << 8) + (c << 4) + sl;
        union { uint4 u; bf16x8 v; } k0_, k1_;
        k0_.u = *(const uint4*)(kbase + (long long)t * 2048);
        k1_.u = *(const uint4*)(kbase + (long long)t * 2048 + 32);
        floatx4 a = (floatx4){0.f, 0.f, 0.f, 0.f};
        a = __builtin_amdgcn_mfma_f32_16x16x32_bf16(k0_.v, qf0, a, 0, 0, 0);
        a = __builtin_amdgcn_mfma_f32_16x16x32_bf16(k1_.v, qf1, a, 0, 0, 0);
        acc[c] = a;
    }

    // scale + mask, row max
    float mx = -__builtin_inff();
#pragma unroll
    for (int c = 0; c < 16; c++) {
        const int tb_ = (w << 8) + (c << 4) + (kq << 2);
        int4 m4 = *(const int4*)&msk[tb_];
#pragma unroll
        for (int r = 0; r < 4; r++) {
            const int mv = (r == 0) ? m4.x : (r == 1) ? m4.y : (r == 2) ? m4.z : m4.w;
            float x = (mv != 0) ? acc[c][r] * 0.03125f : -__builtin_inff();
            acc[c][r] = x;
            mx = fmaxf(mx, x);
        }
    }
    mx = fmaxf(mx, __shfl_xor(mx, 16, 64));
    mx = fmaxf(mx, __shfl_xor(mx, 32, 64));
    if (lane < 16) redM[w][lane] = mx;
    __syncthreads();
    mx = fmaxf(fmaxf(redM[0][sl], redM[1][sl]), fmaxf(redM[2][sl], redM[3][sl]));

    // exp + sum
    float s = 0.f;
#pragma unroll
    for (int c = 0; c < 16; c++)
#pragma unroll
        for (int r = 0; r < 4; r++) {
            const float e = __expf(acc[c][r] - mx);
            acc[c][r] = e;
            s += e;
        }
    s += __shfl_xor(s, 16, 64);
    s += __shfl_xor(s, 32, 64);
    if (lane < 16) redS[w][lane] = s;
    __syncthreads();
    s = redS[0][sl] + redS[1][sl] + redS[2][sl] + redS[3][sl];
    const float sc = lamscale / s;

    float* obase = Aout + (long long)z * 1048576
                 + (long long)(r0 + sl) * 1024 + (w << 8) + (kq << 2);
#pragma unroll
    for (int c = 0; c < 16; c++) {
        floatx4 o = acc[c] * sc;
        *(floatx4*)(obase + (c << 4)) = o;
    }
}

// ---------------------------------------------------------------------------
// Pack kernels (f32 in -> bf16 out)
// ---------------------------------------------------------------------------
// Xbf[i] = bf16(X[i]), 4 elems/thread
__global__ void pack_x(const float* __restrict__ X, u16* __restrict__ dst)
{
    const int i = (blockIdx.x * 256 + threadIdx.x) * 4;
    float4 f = *(const float4*)(X + i);
    u16 o[4] = { f2bf(f.x), f2bf(f.y), f2bf(f.z), f2bf(f.w) };
    *(uint2*)(dst + i) = *(const uint2*)&o[0];
}

// WqkT [2048 n][1024 k]: n<1024 -> WQ1[h=n>>6][k][e=n&63]; else WK1
__global__ void pack_wqkt(const float* __restrict__ WQ, const float* __restrict__ WK,
                          u16* __restrict__ dst)
{
    int i = blockIdx.x * 256 + threadIdx.x;  // 2M
    int k = i & 1023;
    int n = i >> 10;
    float v;
    if (n < 1024) {
        int h = n >> 6, e = n & 63;
        v = WQ[(h * 1024 + k) * 64 + e];
    } else {
        int m = n - 1024; int h = m >> 6, e = m & 63;
        v = WK[(h * 1024 + k) * 64 + e];
    }
    dst[i] = f2bf(v);
}

// WvT [16 h][128 v][1024 d] = WV[h][d][v]
__global__ void pack_wvt(const float* __restrict__ WV, u16* __restrict__ dst)
{
    int i = blockIdx.x * 256 + threadIdx.x;  // 2M
    int d = i & 1023;
    int v = (i >> 10) & 127;
    int h = i >> 17;
    dst[i] = f2bf(WV[(h * 1024 + d) * 128 + v]);
}

// dst[C][R] = bf16(src[R][C]), R = 1<<rlog2
__global__ void transpose_bf(const float* __restrict__ src, u16* __restrict__ dst,
                             int rlog2, int C)
{
    long long i = (long long)blockIdx.x * 256 + threadIdx.x;
    int r = (int)(i & ((1 << rlog2) - 1));
    int c = (int)(i >> rlog2);
    dst[i] = f2bf(src[(long long)r * C + c]);
}

// out = LN(x + add) over 1024; x/add each f32 or bf16 (null-select); out bf16 or f32.
__global__ __launch_bounds__(256) void ln_residual(
    const float* __restrict__ xf, const u16* __restrict__ xbf,
    const float* __restrict__ addf, const u16* __restrict__ addbf,
    const float* __restrict__ w, const float* __restrict__ bb,
    u16* __restrict__ obf, float* __restrict__ of32)
{
    const int row = blockIdx.x;
    const int tid = threadIdx.x;
    const int lane = tid & 63, wid = tid >> 6;
    const long long base = (long long)row * 1024;
    float v[4];
    float s = 0.f;
#pragma unroll
    for (int i = 0; i < 4; i++) {
        const int c = tid * 4 + i;
        float x = xf ? xf[base + c] : bf2f(xbf[base + c]);
        x += addf ? addf[base + c] : bf2f(addbf[base + c]);
        v[i] = x; s += x;
    }
    __shared__ float red[8];
    s = wred_sum(s);
    if (lane == 0) red[wid] = s;
    __syncthreads();
    const float mu = (red[0] + red[1] + red[2] + red[3]) * (1.f / 1024.f);
    float ss = 0.f;
#pragma unroll
    for (int i = 0; i < 4; i++) { const float d = v[i] - mu; ss += d * d; }
    ss = wred_sum(ss);
    if (lane == 0) red[wid + 4] = ss;
    __syncthreads();
    const float var = (red[4] + red[5] + red[6] + red[7]) * (1.f / 1024.f);
    const float inv = rsqrtf(var + 1e-5f);
#pragma unroll
    for (int i = 0; i < 4; i++) {
        const int c = tid * 4 + i;
        const float o = (v[i] - mu) * inv * w[c] + bb[c];
        if (obf) obf[base + c] = f2bf(o);
        else     of32[base + c] = o;
    }
}

// ---------------------------------------------------------------------------
extern "C" void kernel_launch(void* const* d_in, const int* in_sizes, int n_in,
                              void* d_out, int out_size, void* d_ws, size_t ws_size,
                              hipStream_t stream)
{
    const float* X     = (const float*)d_in[0];   // [4,1024,1024]
    const int*   mask  = (const int*)d_in[1];     // [4,1024]
    const float* WQ1   = (const float*)d_in[2];
    const float* bQ1   = (const float*)d_in[3];
    const float* WK1   = (const float*)d_in[4];
    const float* bK1   = (const float*)d_in[5];
    const float* WV    = (const float*)d_in[6];
    const float* bV    = (const float*)d_in[7];
    const float* lnh_w = (const float*)d_in[8];
    const float* lnh_b = (const float*)d_in[9];
    const float* WO    = (const float*)d_in[10];  // [2048,1024]
    const float* bO    = (const float*)d_in[11];
    const float* ln1_w = (const float*)d_in[12];
    const float* ln1_b = (const float*)d_in[13];
    const float* ln2_w = (const float*)d_in[14];
    const float* ln2_b = (const float*)d_in[15];
    const float* W1    = (const float*)d_in[16];  // [1024,4096]
    const float* b1    = (const float*)d_in[17];
    const float* W2    = (const float*)d_in[18];  // [4096,1024]
    const float* b2    = (const float*)d_in[19];
    const float* lq1   = (const float*)d_in[20];
    const float* lk1   = (const float*)d_in[21];
    const float* lq2   = (const float*)d_in[22];
    const float* lk2   = (const float*)d_in[23];

    float* r2   = (float*)d_out;              // [4096,1024] f32, written LAST
    float* Aout = (float*)d_out + 4194304;    // [16,4,1024,1024] f32
    u16*   Vt   = (u16*)d_out;                // Vt scratch in r2 region, dead after PV
    float* ff2  = (float*)d_out;              // ff2 scratch in r2 region, after PV

    // Workspace arena, 48 MB peak (byte offsets; lifetimes in step numbers):
    uint8_t* wp = (uint8_t*)d_ws;
    const size_t MB = 1024 * 1024;
    u16*   WqkT = (u16*)(wp + 0);          //  0..4   [1-3]
    u16*   WvT  = (u16*)(wp + 4 * MB);     //  4..8   [2-4]
    u16*   QK   = (u16*)(wp + 8 * MB);     //  8..24  [3-6]
    u16*   Xbf  = (u16*)(wp + 24 * MB);    // 24..32  [0-4]
    u16*   WOt  = (u16*)(wp + 0);          //  0..4   [5-8]
    u16*   Ocat = (u16*)(wp + 24 * MB);    // 24..40  [7-8]
    u16*   attnb= (u16*)(wp + 8 * MB);     //  8..16  [8-9]
    u16*   h1   = (u16*)(wp + 40 * MB);    // 40..48  [9-12]
    u16*   W1t  = (u16*)(wp + 16 * MB);    // 16..24  [10-11]
    u16*   W2t  = (u16*)(wp + 32 * MB);    // 32..40  [10-11]
    u16*   ff1c = (u16*)(wp + 0);          //  0..16  [11]
    (void)ws_size; (void)in_sizes; (void)n_in; (void)out_size;

    const long long Z = 0;
    const int NOSPLIT = 1 << 30;

    // 0-2. packs
    pack_x<<<4096, 256, 0, stream>>>(X, Xbf);
    pack_wqkt<<<8192, 256, 0, stream>>>(WQ1, WK1, WqkT);
    pack_wvt<<<8192, 256, 0, stream>>>(WV, WvT);

    // 3. QK = Xbf[4096,1024] x WqkT^T + [bQ1|bK1] -> bf16 [4096,2048]
    gemm_bt<FLAG_OUT_BF16 | FLAG_BIAS, 0, 0><<<dim3(16, 32, 1), 256, 0, stream>>>(
        Xbf, 1024, Z, Z, WqkT, 1024, Z, Z, QK, 2048, Z, Z,
        1024, 1, 1.f, bQ1, bK1, 1024, 0, nullptr, 0, nullptr, nullptr);

    // 4. Vt[h][b][v][t] = WvT[h] x Xbf[b]^T + bV[h][v] -> bf16 (in r2 region)
    gemm_bt<FLAG_OUT_BF16 | FLAG_BIAS_ROW, 0, 0><<<dim3(8, 1, 64), 256, 0, stream>>>(
        WvT, 1024, 131072LL, Z, Xbf, 1024, Z, 1048576LL,
        Vt, 1024, 524288LL, 131072LL,
        1024, 4, 1.f, bV, nullptr, NOSPLIT, 128, nullptr, 0, nullptr, nullptr);

    // 5. WOt pack (WqkT region, dead)
    transpose_bf<<<8192, 256, 0, stream>>>(WO, WOt, 11, 1024);

    // 6. fused scores+mask+softmax+(1-lam): A f32 written once
    scores_softmax<<<dim3(64, 1, 64), 256, 0, stream>>>(QK, mask, Aout,
                                                        lq1, lk1, lq2, lk2);

    // 7. PV + fused per-head LN: per (h,b) A[1024,1024](f32) x Vt[128,1024]^T
    //    -> LN(128), *(1-LAMBDA_INIT), scatter to Ocat[b][s][h*128+c] bf16
    gemm_bt<FLAG_LNH, 1, 0><<<dim3(1, 8, 64), 256, 0, stream>>>(
        Aout, 1024, 4194304LL, 1048576LL, Vt, 1024, 524288LL, 131072LL,
        Ocat, 2048, 128LL, 2097152LL,
        1024, 4, 1.f, nullptr, nullptr, NOSPLIT, 0, nullptr, 0, lnh_w, lnh_b);

    // 8. attn = Ocat[4096,2048] x WOt^T + bO -> bf16
    gemm_bt<FLAG_OUT_BF16 | FLAG_BIAS, 0, 0><<<dim3(8, 32, 1), 256, 0, stream>>>(
        Ocat, 2048, Z, Z, WOt, 2048, Z, Z, attnb, 1024, Z, Z,
        2048, 1, 1.f, bO, nullptr, NOSPLIT, 0, nullptr, 0, nullptr, nullptr);

    // 9. h1 = LN(X(f32) + attn(bf16)) -> bf16
    ln_residual<<<4096, 256, 0, stream>>>(X, nullptr, nullptr, attnb,
                                          ln1_w, ln1_b, h1, nullptr);

    // 10. W1t/W2t packs (QK-tail / Ocat regions, dead)
    transpose_bf<<<16384, 256, 0, stream>>>(W1, W1t, 10, 4096);
    transpose_bf<<<16384, 256, 0, stream>>>(W2, W2t, 12, 1024);

    // 11. FFN in 2 hidden-chunks of 2048; ff2 f32 accumulates in r2 region
    for (int c = 0; c < 2; c++) {
        gemm_bt<FLAG_OUT_BF16 | FLAG_BIAS | FLAG_RELU, 0, 0><<<dim3(16, 32, 1), 256, 0, stream>>>(
            h1, 1024, Z, Z, W1t + (long long)c * 2097152, 1024, Z, Z,
            ff1c, 2048, Z, Z,
            1024, 1, 1.f, b1 + c * 2048, nullptr, NOSPLIT, 0, nullptr, 0, nullptr, nullptr);
        if (c == 0) {
            gemm_bt<FLAG_BIAS, 0, 0><<<dim3(8, 32, 1), 256, 0, stream>>>(
                ff1c, 2048, Z, Z, W2t + c * 2048, 4096, Z, Z, ff2, 1024, Z, Z,
                2048, 1, 1.f, b2, nullptr, NOSPLIT, 0, nullptr, 0, nullptr, nullptr);
        } else {
            gemm_bt<FLAG_ACCUM, 0, 0><<<dim3(8, 32, 1), 256, 0, stream>>>(
                ff1c, 2048, Z, Z, W2t + c * 2048, 4096, Z, Z, ff2, 1024, Z, Z,
                2048, 1, 1.f, nullptr, nullptr, NOSPLIT, 0, nullptr, 0, nullptr, nullptr);
        }
    }

    // 12. r2 = LN(h1(bf16) + ff2(f32)) -> f32 d_out (in place over ff2: each
    //     thread reads its elements before writing them; no cross-thread alias)
    ln_residual<<<4096, 256, 0, stream>>>(nullptr, h1, ff2, nullptr,
                                          ln2_w, ln2_b, nullptr, r2);
}